// Round 18
// baseline (717.954 us; speedup 1.0000x reference)
//
#include <hip/hip_runtime.h>

#define A3 180
#define A2 128
#define W2D 384
#define NV 192
#define NU 256
#define VZ 192
#define VY 192
#define VX 192

// cone-BP tile geometry: 32x8 tile, 16 z per thread -> 1728 blocks (6.75/CU).
#define BX 32
#define BY 8
#define CZPT 16
#define WROWS 24       // v window rows (live span <= ~22.5)
#define WDW 64         // u window cols (live span <= ~49 incl. margins+align)

// bp2d tile geometry: 32u x 32v -> per-angle pos span = 31(|c|+|s|) <= 44
#define BU2 32
#define BV2 32
#define VPT2 4
#define PW 64          // staged cols per angle (max rel tap 47 < 64)

static constexpr double PI_D = 3.14159265358979323846;

// async global->LDS; dest = wave-uniform base + lane*size
#define GLOAD16(gaddr, laddr)                                                    \
    __builtin_amdgcn_global_load_lds(                                            \
        (const __attribute__((address_space(1))) unsigned int*)(gaddr),          \
        (__attribute__((address_space(3))) unsigned int*)(laddr), 16, 0, 0)
#define GLOAD4(gaddr, laddr)                                                     \
    __builtin_amdgcn_global_load_lds(                                            \
        (const __attribute__((address_space(1))) unsigned int*)(gaddr),          \
        (__attribute__((address_space(3))) unsigned int*)(laddr), 4, 0, 0)

// ---------------- Kernel T: trig tables ----------------
__global__ void tables_kernel(float* __restrict__ c2, float* __restrict__ s2,
                              float* __restrict__ cbt, float* __restrict__ sbt) {
    int i = threadIdx.x;
    if (i < A2) {
        float th = (float)i * (float)(PI_D / A2);
        c2[i] = cosf(th);
        s2[i] = sinf(th);
    }
    if (i < A3) {
        float be = (float)i * (float)(2.0 * PI_D / A3);
        cbt[i] = cosf(be);
        sbt[i] = sinf(be);
    }
}

// ---------------- Kernel A: d = grad_last(sino * weight) ----------------
__global__ __launch_bounds__(W2D) void grad_kernel(const float* __restrict__ sino,
                                                   const float* __restrict__ wini,
                                                   float* __restrict__ d) {
    __shared__ float p[W2D];
    size_t base = (size_t)blockIdx.x * W2D;
    int w = threadIdx.x;
    p[w] = sino[base + w] * wini[base + w];
    __syncthreads();
    float g;
    if (w == 0)            g = p[1] - p[0];
    else if (w == W2D - 1) g = p[W2D - 1] - p[W2D - 2];
    else                   g = (p[w + 1] - p[w - 1]) * 0.5f;
    d[base + w] = g;
}

// ---------------- Kernel B: 2D parallel BP + cosine weight (LDS window) ----
// (R13 form, proven: plain 2 LDS reads per tap)
__global__ __launch_bounds__(256) void bp2d_kernel(const float* __restrict__ d,
                                                   const float* __restrict__ c2,
                                                   const float* __restrict__ s2,
                                                   float* __restrict__ wcb) {
    __shared__ float rowwin[2][4][PW];
    __shared__ float csl[A2], ssl[A2];
    __shared__ int umin_s[A2];

    int tid = threadIdx.x;
    int ul = tid & 31;
    int vth = tid >> 5;
    int wv = tid >> 6;
    int lane = tid & 63;
    int u0g = blockIdx.x * BU2;
    int v0g = blockIdx.y * BV2;
    int a3 = blockIdx.z;

    float uf = (float)(u0g + ul) - 127.5f;
    float vf0 = (float)(v0g + vth * VPT2) - 95.5f;
    const float* slab = d + (size_t)a3 * (A2 * W2D);

    if (tid < A2) {
        float c = c2[tid], s = s2[tid];
        csl[tid] = c; ssl[tid] = s;
        float cu0 = ((float)u0g - 127.5f) * c;
        float cu1 = ((float)(u0g + BU2 - 1) - 127.5f) * c;
        float cv0 = ((float)v0g - 95.5f) * s;
        float cv1 = ((float)(v0g + BV2 - 1) - 95.5f) * s;
        float m = fminf(cu0, cu1) + fminf(cv0, cv1) + 191.5f;
        umin_s[tid] = (int)m - 2;
    }
    __syncthreads();

    {
        int um = umin_s[wv];
        int colg = min(um + lane, W2D - 1);
        GLOAD4(slab + wv * W2D + colg, &rowwin[0][wv][0]);
    }
    __syncthreads();

    float acc[VPT2];
#pragma unroll
    for (int k = 0; k < VPT2; ++k) acc[k] = 0.0f;

    for (int g = 0; g < A2 / 4; ++g) {
        int buf = g & 1;
        if (g + 1 < A2 / 4) {
            int aa = (g + 1) * 4 + wv;
            int um = umin_s[aa];
            int colg = min(um + lane, W2D - 1);
            GLOAD4(slab + aa * W2D + colg, &rowwin[buf ^ 1][wv][0]);
        }
#pragma unroll
        for (int j = 0; j < 4; ++j) {
            int aa = g * 4 + j;
            float c = csl[aa], s = ssl[aa];
            float pb = fmaf(uf, c, fmaf(vf0, s, 191.5f - (float)umin_s[aa]));
            const float* rw = rowwin[buf][j];
#pragma unroll
            for (int k = 0; k < VPT2; ++k) {
                float pos = fmaf((float)k, s, pb);
                int i0 = (int)pos;
                float f = __builtin_amdgcn_fractf(pos);
                float r0 = rw[i0], r1 = rw[i0 + 1];
                acc[k] = fmaf(f, r1 - r0, acc[k] + r0);
            }
        }
        __syncthreads();
    }

    float x = uf * 2.0f;
    float scale = (float)((PI_D / A2) * (2.0 * PI_D / A3));
#pragma unroll
    for (int k = 0; k < VPT2; ++k) {
        float y = (vf0 + (float)k) * 2.0f;
        float w3 = 1200.0f * __builtin_amdgcn_rsqf(1440000.0f + x * x + y * y);
        int v = v0g + vth * VPT2 + k;
        wcb[((size_t)a3 * NV + v) * NU + u0g + ul] = acc[k] * scale * w3;
    }
}

// ---------------- Kernel C: cone-beam BP ----------------
// 32x8 voxel tile, 16 z per thread, pair-staged 24x64 windows (one barrier
// per 2 betas). u-fused scalar z-walk: carry (cwlo, cwhi) = u-interpolated
// column values; per k -> one ds_read2 (row v0+1), cwn = wa*n0+wb*n1, one
// select, one lerp into a single accumulator.
__global__ __launch_bounds__(256, 8) void conebp_kernel(const float* __restrict__ wcb,
                                                        const float* __restrict__ cbt,
                                                        const float* __restrict__ sbt,
                                                        float* __restrict__ out) {
    __shared__ float win[4][WROWS * WDW];   // 24.5 KB
    __shared__ int orgs_s[A3];

    int tid = threadIdx.x;
    int tx = tid & (BX - 1);
    int ty = tid >> 5;
    int wid = tid >> 6;
    int lane = tid & 63;

    int x = blockIdx.x * BX + tx;
    int y = blockIdx.y * BY + ty;
    int z0 = blockIdx.z * CZPT;

    float xf = (float)x - 95.5f;
    float yf = (float)y - 95.5f;
    float z0f = (float)z0 - 95.5f;

    // ---- one-time: per-beta window origins from block corners ----
    {
        float cxf0 = (float)(blockIdx.x * BX) - 95.5f;
        float cxf1 = cxf0 + (float)(BX - 1);
        float cyf0 = (float)(blockIdx.y * BY) - 95.5f;
        float cyf1 = cyf0 + (float)(BY - 1);
        if (tid < A3) {
            float cbb = cbt[tid], sbb = sbt[tid];
            float iumin = 1e30f, ivmin = 1e30f;
#pragma unroll
            for (int c = 0; c < 4; ++c) {
                float cx = (c & 1) ? cxf1 : cxf0;
                float cy = (c & 2) ? cyf1 : cyf0;
                float rr = cx * cbb + cy * sbb;
                float inv = __builtin_amdgcn_rcpf(750.0f - rr);
                float tt = cy * cbb - cx * sbb;
                iumin = fminf(iumin, fmaf(600.0f * tt, inv, 135.5f));
                ivmin = fminf(ivmin, fmaf(600.0f * z0f, inv, 95.5f));
            }
            int um = (int)iumin - 9;              // floor -8 bias -1 margin
            um = min(max(um, 0), 192) & ~3;       // 16B-aligned, in-bounds
            int vm = min(max((int)ivmin - 1, 1), 168);  // +23 rows stays < 192
            orgs_s[tid] = (vm << 16) | um;
        }
    }
    __syncthreads();

    float acc[CZPT];
#pragma unroll
    for (int k = 0; k < CZPT; ++k) acc[k] = 0.0f;

    // per-lane staging offset (dwords) in GLOBAL window layout:
    // row = wid*4 + (lane>>4), col = 4*(lane&15); global row stride 256.
    unsigned pre = ((unsigned)(lane >> 4) << 8) + ((unsigned)(lane & 15) << 2)
                 + ((unsigned)wid << 10);

    // stage beta b's 24x64 window into win[buf]: rows 0-15 all waves,
    // rows 16-23 waves 0-1.
    auto stage = [&](int b, int buf) {
        int org = orgs_s[b];
        unsigned umin = org & 0xffffu, vmin = (unsigned)org >> 16;
        const float* src = wcb + (size_t)b * (NV * NU) + (vmin << 8) + umin;
        float* dst = &win[buf][0];
        GLOAD16(src + pre, dst + ((unsigned)wid << 8));
        if (wid < 2)
            GLOAD16(src + 4096 + pre, dst + 1024 + ((unsigned)wid << 8));
    };

    // compute beta b from window win[buf] — u-fused scalar z-walk
    auto compute = [&](int b, int buf) {
        float cb = cbt[b], sb = sbt[b];
        float r = fmaf(xf, cb, yf * sb);
        float t = fmaf(yf, cb, -xf * sb);
        float inv = __builtin_amdgcn_rcpf(750.0f - r);
        float dstep = 600.0f * inv;
        float iub = fmaf(t, dstep, 135.5f);          // +8 bias, > 0
        int u0 = (int)iub - 8;
        float fu = __builtin_amdgcn_fractf(iub);
        float wgt = 750.0f * inv;
        wgt *= wgt;                                   // (DSO/denom)^2
        float wa = ((unsigned)u0 < NU) ? (1.0f - fu) * wgt : 0.0f;
        float wb = ((unsigned)(u0 + 1) < NU) ? fu * wgt : 0.0f;

        int org = orgs_s[b];
        unsigned uminc = org & 0xffffu, vminc = (unsigned)org >> 16;
        float ivr = fmaf(dstep, z0f, 95.5f - (float)vminc);   // window-rel >= 1
        const float* w0 = &win[buf][0] + (u0 - (int)uminc);

        int vcur = (int)ivr;                 // v0 at k=0 (ivr > 0)
        int o0 = vcur << 6;
        // u-fused init: cwlo = wa*row(v0) + wb*row(v0)[+1]
        float cwlo = fmaf(wb, w0[o0 + 1], wa * w0[o0]);
        float cwhi = cwlo;                   // dummy; overwritten at k=0

#pragma unroll
        for (int k = 0; k < CZPT; ++k) {
            float iv = fmaf((float)k, dstep, ivr);
            int v0 = (int)iv;                         // trunc == floor
            float fv = __builtin_amdgcn_fractf(iv);
            int on = (v0 + 1) << 6;
            float n0 = w0[on];                        // one ds_read2 per k
            float n1 = w0[on + 1];
            float cwn = fmaf(wb, n1, wa * n0);        // u-fused new row
            cwlo = (v0 != vcur) ? cwhi : cwlo;
            cwhi = cwn;
            vcur = v0;
            acc[k] = fmaf(fv, cwhi - cwlo, acc[k] + cwlo);
        }
    };

    // prologue: stage pair 0
    stage(0, 0);
    stage(1, 1);
    __syncthreads();

    for (int p = 0; p < A3 / 2; ++p) {
        int cur = (p & 1) << 1;          // 0 or 2
        if (p + 1 < A3 / 2) {
            stage(2 * p + 2, cur ^ 2);
            stage(2 * p + 3, (cur ^ 2) + 1);
        }
        compute(2 * p,     cur);
        compute(2 * p + 1, cur + 1);
        __syncthreads();   // drains async staging of pair p+1
    }

#pragma unroll
    for (int k = 0; k < CZPT; ++k) {
        out[(((size_t)(z0 + k)) * VY + y) * VX + x] = acc[k];
    }
}

extern "C" void kernel_launch(void* const* d_in, const int* in_sizes, int n_in,
                              void* d_out, int out_size, void* d_ws, size_t ws_size,
                              hipStream_t stream) {
    const float* sino = (const float*)d_in[0];  // [1,1,A3,A2,W2D] flat
    const float* wini = (const float*)d_in[1];  // [A3,A2,W2D] flat
    float* out = (float*)d_out;                 // [1,VZ,VY,VX] flat

    float* d   = (float*)d_ws;                        // A3*A2*W2D
    float* wcb = d + (size_t)A3 * A2 * W2D;           // A3*NV*NU
    float* c2  = wcb + (size_t)A3 * NV * NU;
    float* s2  = c2 + A2;
    float* cbt = s2 + A2;
    float* sbt = cbt + A3;

    tables_kernel<<<1, 256, 0, stream>>>(c2, s2, cbt, sbt);
    grad_kernel<<<A3 * A2, W2D, 0, stream>>>(sino, wini, d);
    bp2d_kernel<<<dim3(NU / BU2, NV / BV2, A3), 256, 0, stream>>>(d, c2, s2, wcb);
    conebp_kernel<<<dim3(VX / BX, VY / BY, VZ / CZPT), 256, 0, stream>>>(wcb, cbt, sbt, out);
}

// Round 19
// 709.889 us; speedup vs baseline: 1.0114x; 1.0114x over previous
//
#include <hip/hip_runtime.h>

#define A3 180
#define A2 128
#define W2D 384
#define NV 192
#define NU 256
#define VZ 192
#define VY 192
#define VX 192

// cone-BP tile geometry: 32x8 tile, 12 z per thread -> 2304 blocks (9/CU).
// CZPT=12 is the VGPR sweet spot (36 VGPR, 57% occ); 16 crossed the 64-VGPR
// cliff (R18: 68 VGPR, 29% occ, slower).
#define BX 32
#define BY 8
#define CZPT 12
#define WROWS 20       // v window rows (live span <= ~18.6)
#define WDW 64         // u window cols (live span <= ~49 incl. margins+align)

// bp2d tile geometry: 32u x 32v -> per-angle pos span = 31(|c|+|s|) <= 44
#define BU2 32
#define BV2 32
#define VPT2 4
#define PW 64          // staged cols per angle (max rel tap 47 < 64)

static constexpr double PI_D = 3.14159265358979323846;

// async global->LDS; dest = wave-uniform base + lane*size
#define GLOAD16(gaddr, laddr)                                                    \
    __builtin_amdgcn_global_load_lds(                                            \
        (const __attribute__((address_space(1))) unsigned int*)(gaddr),          \
        (__attribute__((address_space(3))) unsigned int*)(laddr), 16, 0, 0)
#define GLOAD4(gaddr, laddr)                                                     \
    __builtin_amdgcn_global_load_lds(                                            \
        (const __attribute__((address_space(1))) unsigned int*)(gaddr),          \
        (__attribute__((address_space(3))) unsigned int*)(laddr), 4, 0, 0)

// ---------------- Kernel T: trig tables ----------------
__global__ void tables_kernel(float* __restrict__ c2, float* __restrict__ s2,
                              float* __restrict__ cbt, float* __restrict__ sbt) {
    int i = threadIdx.x;
    if (i < A2) {
        float th = (float)i * (float)(PI_D / A2);
        c2[i] = cosf(th);
        s2[i] = sinf(th);
    }
    if (i < A3) {
        float be = (float)i * (float)(2.0 * PI_D / A3);
        cbt[i] = cosf(be);
        sbt[i] = sinf(be);
    }
}

// ---------------- Kernel A: d = grad_last(sino * weight) ----------------
__global__ __launch_bounds__(W2D) void grad_kernel(const float* __restrict__ sino,
                                                   const float* __restrict__ wini,
                                                   float* __restrict__ d) {
    __shared__ float p[W2D];
    size_t base = (size_t)blockIdx.x * W2D;
    int w = threadIdx.x;
    p[w] = sino[base + w] * wini[base + w];
    __syncthreads();
    float g;
    if (w == 0)            g = p[1] - p[0];
    else if (w == W2D - 1) g = p[W2D - 1] - p[W2D - 2];
    else                   g = (p[w + 1] - p[w - 1]) * 0.5f;
    d[base + w] = g;
}

// ---------------- Kernel B: 2D parallel BP + cosine weight (LDS window) ----
// (R13 form, proven: plain 2 LDS reads per tap)
__global__ __launch_bounds__(256) void bp2d_kernel(const float* __restrict__ d,
                                                   const float* __restrict__ c2,
                                                   const float* __restrict__ s2,
                                                   float* __restrict__ wcb) {
    __shared__ float rowwin[2][4][PW];
    __shared__ float csl[A2], ssl[A2];
    __shared__ int umin_s[A2];

    int tid = threadIdx.x;
    int ul = tid & 31;
    int vth = tid >> 5;
    int wv = tid >> 6;
    int lane = tid & 63;
    int u0g = blockIdx.x * BU2;
    int v0g = blockIdx.y * BV2;
    int a3 = blockIdx.z;

    float uf = (float)(u0g + ul) - 127.5f;
    float vf0 = (float)(v0g + vth * VPT2) - 95.5f;
    const float* slab = d + (size_t)a3 * (A2 * W2D);

    if (tid < A2) {
        float c = c2[tid], s = s2[tid];
        csl[tid] = c; ssl[tid] = s;
        float cu0 = ((float)u0g - 127.5f) * c;
        float cu1 = ((float)(u0g + BU2 - 1) - 127.5f) * c;
        float cv0 = ((float)v0g - 95.5f) * s;
        float cv1 = ((float)(v0g + BV2 - 1) - 95.5f) * s;
        float m = fminf(cu0, cu1) + fminf(cv0, cv1) + 191.5f;
        umin_s[tid] = (int)m - 2;
    }
    __syncthreads();

    {
        int um = umin_s[wv];
        int colg = min(um + lane, W2D - 1);
        GLOAD4(slab + wv * W2D + colg, &rowwin[0][wv][0]);
    }
    __syncthreads();

    float acc[VPT2];
#pragma unroll
    for (int k = 0; k < VPT2; ++k) acc[k] = 0.0f;

    for (int g = 0; g < A2 / 4; ++g) {
        int buf = g & 1;
        if (g + 1 < A2 / 4) {
            int aa = (g + 1) * 4 + wv;
            int um = umin_s[aa];
            int colg = min(um + lane, W2D - 1);
            GLOAD4(slab + aa * W2D + colg, &rowwin[buf ^ 1][wv][0]);
        }
#pragma unroll
        for (int j = 0; j < 4; ++j) {
            int aa = g * 4 + j;
            float c = csl[aa], s = ssl[aa];
            float pb = fmaf(uf, c, fmaf(vf0, s, 191.5f - (float)umin_s[aa]));
            const float* rw = rowwin[buf][j];
#pragma unroll
            for (int k = 0; k < VPT2; ++k) {
                float pos = fmaf((float)k, s, pb);
                int i0 = (int)pos;
                float f = __builtin_amdgcn_fractf(pos);
                float r0 = rw[i0], r1 = rw[i0 + 1];
                acc[k] = fmaf(f, r1 - r0, acc[k] + r0);
            }
        }
        __syncthreads();
    }

    float x = uf * 2.0f;
    float scale = (float)((PI_D / A2) * (2.0 * PI_D / A3));
#pragma unroll
    for (int k = 0; k < VPT2; ++k) {
        float y = (vf0 + (float)k) * 2.0f;
        float w3 = 1200.0f * __builtin_amdgcn_rsqf(1440000.0f + x * x + y * y);
        int v = v0g + vth * VPT2 + k;
        wcb[((size_t)a3 * NV + v) * NU + u0g + ul] = acc[k] * scale * w3;
    }
}

// ---------------- Kernel C: cone-beam BP ----------------
// 32x8 voxel tile, 12 z per thread, pair-staged 20x64 windows (one barrier
// per 2 betas). u-fused scalar z-walk: carry (cwlo, cwhi) = u-interpolated
// column values; per k -> one ds_read2 (row v0+1), cwn = wa*n0+wb*n1, one
// select, one lerp into a single accumulator.
__global__ __launch_bounds__(256, 8) void conebp_kernel(const float* __restrict__ wcb,
                                                        const float* __restrict__ cbt,
                                                        const float* __restrict__ sbt,
                                                        float* __restrict__ out) {
    __shared__ float win[4][WROWS * WDW];   // 20 KB
    __shared__ int orgs_s[A3];

    int tid = threadIdx.x;
    int tx = tid & (BX - 1);
    int ty = tid >> 5;
    int wid = tid >> 6;
    int lane = tid & 63;

    int x = blockIdx.x * BX + tx;
    int y = blockIdx.y * BY + ty;
    int z0 = blockIdx.z * CZPT;

    float xf = (float)x - 95.5f;
    float yf = (float)y - 95.5f;
    float z0f = (float)z0 - 95.5f;

    // ---- one-time: per-beta window origins from block corners ----
    {
        float cxf0 = (float)(blockIdx.x * BX) - 95.5f;
        float cxf1 = cxf0 + (float)(BX - 1);
        float cyf0 = (float)(blockIdx.y * BY) - 95.5f;
        float cyf1 = cyf0 + (float)(BY - 1);
        if (tid < A3) {
            float cbb = cbt[tid], sbb = sbt[tid];
            float iumin = 1e30f, ivmin = 1e30f;
#pragma unroll
            for (int c = 0; c < 4; ++c) {
                float cx = (c & 1) ? cxf1 : cxf0;
                float cy = (c & 2) ? cyf1 : cyf0;
                float rr = cx * cbb + cy * sbb;
                float inv = __builtin_amdgcn_rcpf(750.0f - rr);
                float tt = cy * cbb - cx * sbb;
                iumin = fminf(iumin, fmaf(600.0f * tt, inv, 135.5f));
                ivmin = fminf(ivmin, fmaf(600.0f * z0f, inv, 95.5f));
            }
            int um = (int)iumin - 9;              // floor -8 bias -1 margin
            um = min(max(um, 0), 192) & ~3;       // 16B-aligned, in-bounds
            int vm = min(max((int)ivmin - 1, 1), 172);  // +19 rows stays < 192
            orgs_s[tid] = (vm << 16) | um;
        }
    }
    __syncthreads();

    float acc[CZPT];
#pragma unroll
    for (int k = 0; k < CZPT; ++k) acc[k] = 0.0f;

    // per-lane staging offset (dwords) in GLOBAL window layout:
    // row = wid*4 + (lane>>4), col = 4*(lane&15); global row stride 256.
    unsigned pre = ((unsigned)(lane >> 4) << 8) + ((unsigned)(lane & 15) << 2)
                 + ((unsigned)wid << 10);

    // stage beta b's 20x64 window into win[buf]: rows 0-15 all waves,
    // rows 16-19 wave 0 only.
    auto stage = [&](int b, int buf) {
        int org = orgs_s[b];
        unsigned umin = org & 0xffffu, vmin = (unsigned)org >> 16;
        const float* src = wcb + (size_t)b * (NV * NU) + (vmin << 8) + umin;
        float* dst = &win[buf][0];
        GLOAD16(src + pre, dst + ((unsigned)wid << 8));
        if (wid == 0)
            GLOAD16(src + 4096 + pre, dst + 1024);   // rows 16..19
    };

    // compute beta b from window win[buf] — u-fused scalar z-walk
    auto compute = [&](int b, int buf) {
        float cb = cbt[b], sb = sbt[b];
        float r = fmaf(xf, cb, yf * sb);
        float t = fmaf(yf, cb, -xf * sb);
        float inv = __builtin_amdgcn_rcpf(750.0f - r);
        float dstep = 600.0f * inv;
        float iub = fmaf(t, dstep, 135.5f);          // +8 bias, > 0
        int u0 = (int)iub - 8;
        float fu = __builtin_amdgcn_fractf(iub);
        float wgt = 750.0f * inv;
        wgt *= wgt;                                   // (DSO/denom)^2
        float wa = ((unsigned)u0 < NU) ? (1.0f - fu) * wgt : 0.0f;
        float wb = ((unsigned)(u0 + 1) < NU) ? fu * wgt : 0.0f;

        int org = orgs_s[b];
        unsigned uminc = org & 0xffffu, vminc = (unsigned)org >> 16;
        float ivr = fmaf(dstep, z0f, 95.5f - (float)vminc);   // window-rel >= 1
        const float* w0 = &win[buf][0] + (u0 - (int)uminc);

        int vcur = (int)ivr;                 // v0 at k=0 (ivr > 0)
        int o0 = vcur << 6;
        // u-fused init: cwlo = wa*row(v0) + wb*row(v0)[+1]
        float cwlo = fmaf(wb, w0[o0 + 1], wa * w0[o0]);
        float cwhi = cwlo;                   // dummy; overwritten at k=0

#pragma unroll
        for (int k = 0; k < CZPT; ++k) {
            float iv = fmaf((float)k, dstep, ivr);
            int v0 = (int)iv;                         // trunc == floor
            float fv = __builtin_amdgcn_fractf(iv);
            int on = (v0 + 1) << 6;
            float n0 = w0[on];                        // one ds_read2 per k
            float n1 = w0[on + 1];
            float cwn = fmaf(wb, n1, wa * n0);        // u-fused new row
            cwlo = (v0 != vcur) ? cwhi : cwlo;
            cwhi = cwn;
            vcur = v0;
            acc[k] = fmaf(fv, cwhi - cwlo, acc[k] + cwlo);
        }
    };

    // prologue: stage pair 0
    stage(0, 0);
    stage(1, 1);
    __syncthreads();

    for (int p = 0; p < A3 / 2; ++p) {
        int cur = (p & 1) << 1;          // 0 or 2
        if (p + 1 < A3 / 2) {
            stage(2 * p + 2, cur ^ 2);
            stage(2 * p + 3, (cur ^ 2) + 1);
        }
        compute(2 * p,     cur);
        compute(2 * p + 1, cur + 1);
        __syncthreads();   // drains async staging of pair p+1
    }

#pragma unroll
    for (int k = 0; k < CZPT; ++k) {
        out[(((size_t)(z0 + k)) * VY + y) * VX + x] = acc[k];
    }
}

extern "C" void kernel_launch(void* const* d_in, const int* in_sizes, int n_in,
                              void* d_out, int out_size, void* d_ws, size_t ws_size,
                              hipStream_t stream) {
    const float* sino = (const float*)d_in[0];  // [1,1,A3,A2,W2D] flat
    const float* wini = (const float*)d_in[1];  // [A3,A2,W2D] flat
    float* out = (float*)d_out;                 // [1,VZ,VY,VX] flat

    float* d   = (float*)d_ws;                        // A3*A2*W2D
    float* wcb = d + (size_t)A3 * A2 * W2D;           // A3*NV*NU
    float* c2  = wcb + (size_t)A3 * NV * NU;
    float* s2  = c2 + A2;
    float* cbt = s2 + A2;
    float* sbt = cbt + A3;

    tables_kernel<<<1, 256, 0, stream>>>(c2, s2, cbt, sbt);
    grad_kernel<<<A3 * A2, W2D, 0, stream>>>(sino, wini, d);
    bp2d_kernel<<<dim3(NU / BU2, NV / BV2, A3), 256, 0, stream>>>(d, c2, s2, wcb);
    conebp_kernel<<<dim3(VX / BX, VY / BY, VZ / CZPT), 256, 0, stream>>>(wcb, cbt, sbt, out);
}